// Round 4
// baseline (315.900 us; speedup 1.0000x reference)
//
#include <hip/hip_runtime.h>

// expRNN/modReLU recurrence, B=8192, T=784, I=1, H=30, C=10.
//
// Round 4: mov_dpp + packed-f32 FMA.
//   - 2048 blocks x 1 wave; lane=(bg<<4)|lid; 16 lanes/batch; lane owns
//     h rows r0=2*lid, r1=2*lid+1 as halves of one v2f pair h2. 2 waves/SIMD.
//   - step s(1..15): chunk c=(lid-s)&15 arrives via 2x v_mov_b32_dpp
//     row_ror:s (update_dpp builtin, bound_ctrl=1 -> undef old, no extra
//     mov; compiler handles the VALU->DPP 2-wait-state hazard), then
//     2x v_pk_fma_f32 consume the pair (2 MACs/instr).
//   - Rationale vs R3: measured DPP ops issue at ~half rate; 60 DPP-fmacs
//     -> 30 DPP movs + 32 pk ops is >= as good in every rate scenario.
//   - W (32 v2f pairs = 64 VGPRs) pinned in registers via asm barriers:
//     R3's VGPR_Count=68 showed the compiler was re-loading W from LDS
//     in-loop. Expect ~90-110 VGPRs now (diagnostic).
//   - x enters via scalar fmaf in the epilogue: zz = w_ih*x + z.x + z.y.

#define T_STEPS 784
#define NBATCH  8192
#define NH      30
#define NC      10
#define BPW     4     // batches per wave/block
#define NCH     16    // chunks of 2 rows (rows 30,31 = zero pads)

typedef float v2f __attribute__((ext_vector_type(2)));

#define ROR(dst, src, S) \
    dst = __int_as_float(__builtin_amdgcn_update_dpp( \
        0, __float_as_int(src), 0x120 + (S), 0xf, 0xf, true))

#define PIN8(a,b,c,d,e,f,g,h) \
    asm volatile("" : "+v"(a),"+v"(b),"+v"(c),"+v"(d), \
                      "+v"(e),"+v"(f),"+v"(g),"+v"(h))

__global__ __launch_bounds__(64, 2)
void rnn_modrelu_pk(const float* __restrict__ inp,    // [B, T, 1]
                    const float* __restrict__ W_ih,   // [H, 1]
                    const float* __restrict__ W_hh,   // [H, H]
                    const float* __restrict__ b_mod,  // [H]
                    const float* __restrict__ W_lin,  // [C, H]
                    const float* __restrict__ b_lin,  // [C]
                    float* __restrict__ out)          // [B, C]
{
    __shared__ __align__(16) float xl[BPW * T_STEPS];  // 12.5 KB
    __shared__ __align__(16) float wl[NH * NH];        // 3.6 KB
    __shared__ float hl[BPW * 32];

    const int l   = threadIdx.x;
    const int blk = blockIdx.x;
    const int lid = l & 15;            // chunk index
    const int bg  = l >> 4;            // local batch 0..3

    // ---- preload x: 4 batches x 784 floats, coalesced float4 ----
    {
        const float4* src = (const float4*)(inp + (size_t)blk * (BPW * T_STEPS));
        float4* dst = (float4*)xl;
        #pragma unroll
        for (int k = 0; k < 13; ++k) {
            int idx = l + 64 * k;
            if (idx < (BPW * T_STEPS) / 4) dst[idx] = src[idx];
        }
    }
    // ---- stage W_hh to LDS (coalesced) ----
    {
        const float4* src = (const float4*)W_hh;
        float4* dst = (float4*)wl;
        #pragma unroll
        for (int k = 0; k < 4; ++k) {
            int idx = l + 64 * k;
            if (idx < (NH * NH) / 4) dst[idx] = src[idx];
        }
    }
    __syncthreads();

    // ---- per-lane pre-rotated W pairs: step s uses chunk c=(lid-s)&15 ----
    const int r0 = 2 * lid, r1 = r0 + 1;
    const bool a0 = (r0 < NH), a1 = (r1 < NH);   // lane 15: rows 30,31 pad
    v2f wa[NCH], wb[NCH];
    #pragma unroll
    for (int s = 0; s < NCH; ++s) {
        const int c = (lid - s) & 15;            // c==15 -> dead chunk
        const bool cv = (c < 15);
        wa[s][0] = (a0 && cv) ? wl[r0 * NH + 2 * c]     : 0.0f;
        wa[s][1] = (a0 && cv) ? wl[r0 * NH + 2 * c + 1] : 0.0f;
        wb[s][0] = (a1 && cv) ? wl[r1 * NH + 2 * c]     : 0.0f;
        wb[s][1] = (a1 && cv) ? wl[r1 * NH + 2 * c + 1] : 0.0f;
    }
    // pin W in VGPRs (stop the compiler re-loading from LDS in-loop)
    PIN8(wa[0], wa[1], wa[2],  wa[3],  wa[4],  wa[5],  wa[6],  wa[7]);
    PIN8(wa[8], wa[9], wa[10], wa[11], wa[12], wa[13], wa[14], wa[15]);
    PIN8(wb[0], wb[1], wb[2],  wb[3],  wb[4],  wb[5],  wb[6],  wb[7]);
    PIN8(wb[8], wb[9], wb[10], wb[11], wb[12], wb[13], wb[14], wb[15]);

    const float wih0 = a0 ? W_ih[r0] : 0.0f;
    const float wih1 = a1 ? W_ih[r1] : 0.0f;
    const float bm0  = a0 ? b_mod[r0] : 0.0f;
    const float bm1  = a1 ? b_mod[r1] : 0.0f;

    const float* xb = &xl[bg * T_STEPS];
    float xcur = xb[0];
    v2f h2 = {0.0f, 0.0f};             // own chunk (rows r0, r1)

    #pragma unroll 1
    for (int t = 0; t < T_STEPS; ++t) {
        int tn = t + 1; if (tn >= T_STEPS) tn = T_STEPS - 1;
        const float xnext = xb[tn];    // broadcast b32, waited next iter

        // s = 0: own chunk, plain packed mul (accumulator init)
        v2f z0, z1;
        asm("v_pk_mul_f32 %0, %1, %2" : "=v"(z0) : "v"(wa[0]), "v"(h2));
        asm("v_pk_mul_f32 %0, %1, %2" : "=v"(z1) : "v"(wb[0]), "v"(h2));

#define STEP(S) { \
        v2f q; \
        ROR(q[0], h2[0], S); \
        ROR(q[1], h2[1], S); \
        asm("v_pk_fma_f32 %0, %1, %2, %0" : "+v"(z0) : "v"(wa[S]), "v"(q)); \
        asm("v_pk_fma_f32 %0, %1, %2, %0" : "+v"(z1) : "v"(wb[S]), "v"(q)); \
}
        STEP(1)  STEP(2)  STEP(3)  STEP(4)  STEP(5)
        STEP(6)  STEP(7)  STEP(8)  STEP(9)  STEP(10)
        STEP(11) STEP(12) STEP(13) STEP(14) STEP(15)
#undef STEP

        // horizontal + x term + modReLU (plain C; compiler emits
        // v_add(|z|,b)/v_max/v_bfi and handles the ->DPP hazard next iter)
        float zz0 = fmaf(wih0, xcur, z0[0] + z0[1]);
        float zz1 = fmaf(wih1, xcur, z1[0] + z1[1]);
        h2[0] = copysignf(fmaxf(fabsf(zz0) + bm0, 0.0f), zz0);
        h2[1] = copysignf(fmaxf(fabsf(zz1) + bm1, 0.0f), zz1);

        xcur = xnext;
    }

    // ---- stash h to LDS for the classifier head ----
    hl[bg * 32 + r0] = h2[0];
    hl[bg * 32 + r1] = h2[1];
    __syncthreads();

    // ---- classifier: 40 outputs (4 batches x 10 classes) ----
    if (l < BPW * NC) {
        const int bbo = l / NC;
        const int c   = l % NC;
        float acc = b_lin[c];
        #pragma unroll
        for (int i = 0; i < NH; ++i) {
            acc = fmaf(W_lin[c * NH + i], hl[bbo * 32 + i], acc);
        }
        out[((size_t)blk * BPW + bbo) * NC + c] = acc;
    }
}

extern "C" void kernel_launch(void* const* d_in, const int* in_sizes, int n_in,
                              void* d_out, int out_size, void* d_ws, size_t ws_size,
                              hipStream_t stream) {
    const float* inp   = (const float*)d_in[0];
    const float* W_ih  = (const float*)d_in[1];
    const float* W_hh  = (const float*)d_in[2];
    const float* b_mod = (const float*)d_in[3];
    const float* W_lin = (const float*)d_in[4];
    const float* b_lin = (const float*)d_in[5];
    float* out = (float*)d_out;

    dim3 grid(NBATCH / BPW);   // 2048 blocks
    dim3 block(64);            // one wave
    rnn_modrelu_pk<<<grid, block, 0, stream>>>(inp, W_ih, W_hh, b_mod,
                                               W_lin, b_lin, out);
}

// Round 5
// 250.427 us; speedup vs baseline: 1.2614x; 1.2614x over previous
//
#include <hip/hip_runtime.h>

// expRNN/modReLU recurrence, B=8192, T=784, I=1, H=30, C=10.
//
// Round 5: L=8 lanes/batch, plain-fma MAC stream, minimal DPP count.
// Measured instr-cost model (fit R2/R3/R4): plain f32 VALU = 2 cyc/wave,
// DPP-modified ops = 4 cyc, v_pk_*_f32 = 4 cyc (no win over plain fma).
// => minimize DPP count and use scalar v_fmac_f32 for MACs.
//   - 1024 blocks x 1 wave; 8 batches/block. lane l: w=l&15, row16=l>>4;
//     parity p=w&1, u=w>>1. Local batch bl=2*row16+p; lane owns rows
//     4u..4u+3 of batch bl. Batches interleaved by parity within each
//     16-lane DPP row => row_ror:2s rotates both 8-lane groups at once
//     (u' = u-s mod 8; same verified row_ror direction as R2-R4).
//   - Per step: 4 init-mul (x term) + 16 own-chunk fma + 7x(4 mov_dpp +
//     16 fma) + 12 modrelu ~= 410 issue cyc at 1 wave/SIMD.
//   - W: 128 VGPRs/lane, pre-rotated (wq[s][r][j] = W[4u+r][4*((u-s)&7)+j]),
//     rows/cols >=30 zero-padded. x via accumulator init z=W_ih[row]*x.
//   - 1024 blocks = 4 waves/CU = 1 wave/SIMD (intentional; single wave can
//     saturate VALU issue; 4 z-chains give dep slack).

#define T_STEPS 784
#define NBATCH  8192
#define NH      30
#define NC      10
#define BPB     8     // batches per block
#define XPAD    788   // padded x row: 788%4==0 (float4 LDS) and
                      // 788%32==20 -> 8 batch rows hit distinct banks

typedef float v2f __attribute__((ext_vector_type(2)));

// lane receives value from lane (w - 2S) & 15 within its 16-lane row
#define ROR2(dst, src, S) \
    dst = __int_as_float(__builtin_amdgcn_update_dpp( \
        0, __float_as_int(src), 0x120 + 2*(S), 0xf, 0xf, true))

#define PIN8(a,b,c,d,e,f,g,h) \
    asm volatile("" : "+v"(a),"+v"(b),"+v"(c),"+v"(d), \
                      "+v"(e),"+v"(f),"+v"(g),"+v"(h))

__global__ __launch_bounds__(64, 1)
void rnn_modrelu_l8(const float* __restrict__ inp,    // [B, T, 1]
                    const float* __restrict__ W_ih,   // [H, 1]
                    const float* __restrict__ W_hh,   // [H, H]
                    const float* __restrict__ b_mod,  // [H]
                    const float* __restrict__ W_lin,  // [C, H]
                    const float* __restrict__ b_lin,  // [C]
                    float* __restrict__ out)          // [B, C]
{
    __shared__ __align__(16) float xl[BPB * XPAD];   // 25.2 KB
    __shared__ __align__(16) float wl[NH * NH];      // 3.6 KB
    __shared__ float hfin[BPB * 32];

    const int l     = threadIdx.x;
    const int blk   = blockIdx.x;
    const int w16   = l & 15;
    const int row16 = l >> 4;
    const int u     = w16 >> 1;          // 8-lane sub-index (chunk owner)
    const int bl    = 2 * row16 + (w16 & 1);  // local batch 0..7

    // ---- preload x (8 batches x 784), padded rows, coalesced float4 ----
    {
        const float4* src = (const float4*)(inp + (size_t)blk * (BPB * T_STEPS));
        #pragma unroll
        for (int k = 0; k < 25; ++k) {
            int v = l + 64 * k;                 // float4 index, < 1568
            if (v < (BPB * T_STEPS) / 4) {
                int b   = v / 196;              // 196 float4 per batch row
                int rem = v - b * 196;
                *(float4*)(xl + b * XPAD + 4 * rem) = src[v];
            }
        }
    }
    // ---- stage W_hh to LDS (coalesced) ----
    {
        const float4* src = (const float4*)W_hh;
        #pragma unroll
        for (int k = 0; k < 4; ++k) {
            int idx = l + 64 * k;
            if (idx < (NH * NH) / 4) ((float4*)wl)[idx] = src[idx];
        }
    }
    __syncthreads();

    // ---- per-lane pre-rotated W: step s consumes chunk c=(u-s)&7 ----
    const int r0 = 4 * u;                // first owned row
    float wq[8][4][4];
    #pragma unroll
    for (int s = 0; s < 8; ++s) {
        const int c = (u - s) & 7;
        #pragma unroll
        for (int r = 0; r < 4; ++r) {
            const int row = r0 + r;
            #pragma unroll
            for (int j = 0; j < 4; ++j) {
                const int col = 4 * c + j;
                wq[s][r][j] = (row < NH && col < NH) ? wl[row * NH + col] : 0.0f;
            }
        }
    }
    float wih[4], bm[4];
    #pragma unroll
    for (int r = 0; r < 4; ++r) {
        const int row = r0 + r;
        wih[r] = (row < NH) ? W_ih[row]  : 0.0f;
        bm[r]  = (row < NH) ? b_mod[row] : 0.0f;
    }
    // pin W in VGPRs
    #pragma unroll
    for (int s = 0; s < 8; ++s) {
        PIN8(wq[s][0][0], wq[s][0][1], wq[s][0][2], wq[s][0][3],
             wq[s][1][0], wq[s][1][1], wq[s][1][2], wq[s][1][3]);
        PIN8(wq[s][2][0], wq[s][2][1], wq[s][2][2], wq[s][2][3],
             wq[s][3][0], wq[s][3][1], wq[s][3][2], wq[s][3][3]);
    }

    const float* xb = xl + bl * XPAD;
    float xcur = xb[0];
    float h0 = 0.0f, h1 = 0.0f, h2 = 0.0f, h3 = 0.0f;  // own rows r0..r0+3

    #pragma unroll 1
    for (int t = 0; t < T_STEPS; ++t) {
        int tn = t + 1; if (tn >= T_STEPS) tn = T_STEPS - 1;
        const float xnext = xb[tn];      // 1 ds_read, conflict-free banks

        // accumulator init carries the x term (no augmentation)
        float z0 = wih[0] * xcur;
        float z1 = wih[1] * xcur;
        float z2 = wih[2] * xcur;
        float z3 = wih[3] * xcur;

        // s = 0: own chunk
        #pragma unroll
        for (int j = 0; j < 4; ++j) {
            const float q = (j == 0) ? h0 : (j == 1) ? h1 : (j == 2) ? h2 : h3;
            z0 = fmaf(wq[0][0][j], q, z0);
            z1 = fmaf(wq[0][1][j], q, z1);
            z2 = fmaf(wq[0][2][j], q, z2);
            z3 = fmaf(wq[0][3][j], q, z3);
        }

#define SSTEP(S) { \
        float q0, q1, q2, q3; \
        ROR2(q0, h0, S); ROR2(q1, h1, S); ROR2(q2, h2, S); ROR2(q3, h3, S); \
        z0 = fmaf(wq[S][0][0], q0, z0); z1 = fmaf(wq[S][1][0], q0, z1); \
        z2 = fmaf(wq[S][2][0], q0, z2); z3 = fmaf(wq[S][3][0], q0, z3); \
        z0 = fmaf(wq[S][0][1], q1, z0); z1 = fmaf(wq[S][1][1], q1, z1); \
        z2 = fmaf(wq[S][2][1], q1, z2); z3 = fmaf(wq[S][3][1], q1, z3); \
        z0 = fmaf(wq[S][0][2], q2, z0); z1 = fmaf(wq[S][1][2], q2, z1); \
        z2 = fmaf(wq[S][2][2], q2, z2); z3 = fmaf(wq[S][3][2], q2, z3); \
        z0 = fmaf(wq[S][0][3], q3, z0); z1 = fmaf(wq[S][1][3], q3, z1); \
        z2 = fmaf(wq[S][2][3], q3, z2); z3 = fmaf(wq[S][3][3], q3, z3); \
}
        SSTEP(1) SSTEP(2) SSTEP(3) SSTEP(4) SSTEP(5) SSTEP(6) SSTEP(7)
#undef SSTEP

        // modReLU (pad rows: w==0,b==0 -> stay exactly 0)
        h0 = copysignf(fmaxf(fabsf(z0) + bm[0], 0.0f), z0);
        h1 = copysignf(fmaxf(fabsf(z1) + bm[1], 0.0f), z1);
        h2 = copysignf(fmaxf(fabsf(z2) + bm[2], 0.0f), z2);
        h3 = copysignf(fmaxf(fabsf(z3) + bm[3], 0.0f), z3);

        xcur = xnext;
    }

    // ---- stash h for classifier ----
    hfin[bl * 32 + r0 + 0] = h0;
    hfin[bl * 32 + r0 + 1] = h1;
    hfin[bl * 32 + r0 + 2] = h2;
    hfin[bl * 32 + r0 + 3] = h3;
    __syncthreads();

    // ---- classifier: 80 outputs (8 batches x 10 classes) ----
    #pragma unroll
    for (int it = 0; it < 2; ++it) {
        const int k = l + 64 * it;
        if (k < BPB * NC) {
            const int bbo = k / NC;
            const int c   = k % NC;
            float acc = b_lin[c];
            #pragma unroll
            for (int i = 0; i < NH; ++i) {
                acc = fmaf(W_lin[c * NH + i], hfin[bbo * 32 + i], acc);
            }
            out[((size_t)blk * BPB + bbo) * NC + c] = acc;
        }
    }
}

extern "C" void kernel_launch(void* const* d_in, const int* in_sizes, int n_in,
                              void* d_out, int out_size, void* d_ws, size_t ws_size,
                              hipStream_t stream) {
    const float* inp   = (const float*)d_in[0];
    const float* W_ih  = (const float*)d_in[1];
    const float* W_hh  = (const float*)d_in[2];
    const float* b_mod = (const float*)d_in[3];
    const float* W_lin = (const float*)d_in[4];
    const float* b_lin = (const float*)d_in[5];
    float* out = (float*)d_out;

    dim3 grid(NBATCH / BPB);   // 1024 blocks
    dim3 block(64);            // one wave
    rnn_modrelu_l8<<<grid, block, 0, stream>>>(inp, W_ih, W_hh, b_mod,
                                               W_lin, b_lin, out);
}